// Round 2
// baseline (843.053 us; speedup 1.0000x reference)
//
#include <hip/hip_runtime.h>
#include <hip/hip_bf16.h>

// adLIF: Wx = x @ W^T (fp32 FMA GEMM, strictly sequential-K accumulation to
// mirror BLAS), then sequential LIF scan over T with rounding-exact fp32 ops.
// Dtype of inputs (fp32 vs bf16-converted) is detected ON DEVICE from the bit
// pattern of x's first 64 words; all kernels branch uniformly on it.
// B=128, T=512, I=512, H=512. ws holds Wx fp32 [B,T,H] = 134217728 bytes.

#define M_SZ 65536  // B*T
#define N_SZ 512    // H
#define K_SZ 512    // I
#define B_SZ 128
#define T_SZ 512

// Returns true if the buffer is packed bf16, false if fp32.
// Bits 14..7 of a word: bf16 -> exponent of element 2i (in [115,131] for ~all
// N(0,1)/U(0,1) values); fp32 -> middle mantissa bits (uniform, ~6% in range).
__device__ __forceinline__ bool detect_bf16(const unsigned int* __restrict__ w) {
  int c = 0;
#pragma unroll
  for (int i = 0; i < 64; ++i) {
    unsigned int e = (w[i] >> 7) & 0xffu;
    c += (e >= 115u && e <= 131u) ? 1 : 0;
  }
  return c > 32;
}

// Load 4 consecutive elements (element index `off`) as fp32 under either dtype.
__device__ __forceinline__ float4 ld4(const void* __restrict__ p, size_t off, bool isb) {
  if (!isb) return *reinterpret_cast<const float4*>(reinterpret_cast<const float*>(p) + off);
  uint2 v = *reinterpret_cast<const uint2*>(reinterpret_cast<const unsigned short*>(p) + off);
  float4 r;
  r.x = __uint_as_float((v.x & 0xffffu) << 16);
  r.y = __uint_as_float(v.x & 0xffff0000u);
  r.z = __uint_as_float((v.y & 0xffffu) << 16);
  r.w = __uint_as_float(v.y & 0xffff0000u);
  return r;
}

__device__ __forceinline__ float ld1(const void* __restrict__ p, int i, bool isb) {
  if (!isb) return reinterpret_cast<const float*>(p)[i];
  return __uint_as_float((unsigned int)(reinterpret_cast<const unsigned short*>(p)[i]) << 16);
}

// C[m][n] = sum_k X[m][k] * W[n][k], fp32 accumulate, k strictly ascending,
// one FMA per k per output element (matches BLAS microkernel arithmetic).
// 128x128 tile / block, 256 threads, 8x8 per thread, KS=16.
__global__ __launch_bounds__(256) void sgemm_bt(const void* __restrict__ X,
                                                const void* __restrict__ Wm,
                                                float* __restrict__ C) {
  __shared__ __align__(16) float As[16 * 128];
  __shared__ __align__(16) float Bs[16 * 128];
  const bool isb = detect_bf16(reinterpret_cast<const unsigned int*>(X));
  const int tid = threadIdx.x;
  const int tx = tid & 15;
  const int ty = tid >> 4;
  const size_t M0 = (size_t)(blockIdx.x >> 2) * 128;
  const int N0 = (blockIdx.x & 3) * 128;
  const int r0 = tid >> 2;       // 0..63: staged row within tile
  const int q0 = (tid & 3) * 4;  // 0,4,8,12: k-offset of the 4-elem group

  const size_t aoff0 = (M0 + r0) * K_SZ + q0;
  const size_t aoff1 = (M0 + r0 + 64) * K_SZ + q0;
  const size_t boff0 = (size_t)(N0 + r0) * K_SZ + q0;
  const size_t boff1 = (size_t)(N0 + r0 + 64) * K_SZ + q0;

  float acc[8][8];
#pragma unroll
  for (int i = 0; i < 8; ++i)
#pragma unroll
    for (int j = 0; j < 8; ++j) acc[i][j] = 0.0f;

  float4 pa0 = ld4(X, aoff0, isb);
  float4 pa1 = ld4(X, aoff1, isb);
  float4 pb0 = ld4(Wm, boff0, isb);
  float4 pb1 = ld4(Wm, boff1, isb);

  for (int kk = 0; kk < K_SZ; kk += 16) {
    __syncthreads();  // LDS free (prior reads done)
    As[(q0 + 0) * 128 + r0] = pa0.x;
    As[(q0 + 1) * 128 + r0] = pa0.y;
    As[(q0 + 2) * 128 + r0] = pa0.z;
    As[(q0 + 3) * 128 + r0] = pa0.w;
    As[(q0 + 0) * 128 + r0 + 64] = pa1.x;
    As[(q0 + 1) * 128 + r0 + 64] = pa1.y;
    As[(q0 + 2) * 128 + r0 + 64] = pa1.z;
    As[(q0 + 3) * 128 + r0 + 64] = pa1.w;
    Bs[(q0 + 0) * 128 + r0] = pb0.x;
    Bs[(q0 + 1) * 128 + r0] = pb0.y;
    Bs[(q0 + 2) * 128 + r0] = pb0.z;
    Bs[(q0 + 3) * 128 + r0] = pb0.w;
    Bs[(q0 + 0) * 128 + r0 + 64] = pb1.x;
    Bs[(q0 + 1) * 128 + r0 + 64] = pb1.y;
    Bs[(q0 + 2) * 128 + r0 + 64] = pb1.z;
    Bs[(q0 + 3) * 128 + r0 + 64] = pb1.w;
    __syncthreads();  // tile ready
    if (kk + 16 < K_SZ) {  // prefetch next tile; latency hidden by compute
      pa0 = ld4(X, aoff0 + kk + 16, isb);
      pa1 = ld4(X, aoff1 + kk + 16, isb);
      pb0 = ld4(Wm, boff0 + kk + 16, isb);
      pb1 = ld4(Wm, boff1 + kk + 16, isb);
    }
#pragma unroll
    for (int k = 0; k < 16; ++k) {
      const float4 a0 = *reinterpret_cast<const float4*>(As + k * 128 + ty * 4);
      const float4 a1 = *reinterpret_cast<const float4*>(As + k * 128 + 64 + ty * 4);
      const float4 b0 = *reinterpret_cast<const float4*>(Bs + k * 128 + tx * 4);
      const float4 b1 = *reinterpret_cast<const float4*>(Bs + k * 128 + 64 + tx * 4);
      const float av[8] = {a0.x, a0.y, a0.z, a0.w, a1.x, a1.y, a1.z, a1.w};
      const float bv[8] = {b0.x, b0.y, b0.z, b0.w, b1.x, b1.y, b1.z, b1.w};
#pragma unroll
      for (int i = 0; i < 8; ++i)
#pragma unroll
        for (int j = 0; j < 8; ++j) acc[i][j] += av[i] * bv[j];  // contracts to FMA
    }
  }

#pragma unroll
  for (int r = 0; r < 8; ++r) {
    const size_t m = M0 + ((r < 4) ? (ty * 4 + r) : (64 + ty * 4 + (r - 4)));
    float* Cp = C + m * N_SZ + N0;
    float4 v0 = {acc[r][0], acc[r][1], acc[r][2], acc[r][3]};
    float4 v1 = {acc[r][4], acc[r][5], acc[r][6], acc[r][7]};
    *reinterpret_cast<float4*>(Cp + tx * 4) = v0;
    *reinterpret_cast<float4*>(Cp + 64 + tx * 4) = v1;
  }
}

// One thread per (b,h); rounding-exact fp32 recurrence (no FMA contraction) so
// the scan is bit-identical to numpy given identical Wx. 16-deep prefetch ring.
__global__ __launch_bounds__(256) void lif_scan(
    const float* __restrict__ wx, const void* __restrict__ X,
    const void* __restrict__ alpha_p, const void* __restrict__ beta_p,
    const void* __restrict__ a_p, const void* __restrict__ b_p,
    const void* __restrict__ u0p, const void* __restrict__ w0p,
    const void* __restrict__ s0p, void* __restrict__ out) {
  const bool isb = detect_bf16(reinterpret_cast<const unsigned int*>(X));
  const int bb = blockIdx.x >> 1;
  const int h = ((blockIdx.x & 1) << 8) | threadIdx.x;

  const float al = fminf(fmaxf(ld1(alpha_p, h, isb), (float)0.8187307530779818),
                         (float)0.9607894391523232);
  const float be = fminf(fmaxf(ld1(beta_p, h, isb), (float)0.9672161004820059),
                         (float)0.9917013044213351);
  const float av = fminf(fmaxf(ld1(a_p, h, isb), -1.0f), 1.0f);
  const float bv = fminf(fmaxf(ld1(b_p, h, isb), 0.0f), 2.0f);
  const float om = __fsub_rn(1.0f, al);

  const int bh = bb * N_SZ + h;
  float u = ld1(u0p, bh, isb);
  float w = ld1(w0p, bh, isb);
  float s = ld1(s0p, bh, isb);

  const float* base = wx + (size_t)bb * T_SZ * N_SZ + h;
  const size_t obase = (size_t)bb * T_SZ * N_SZ + h;
  float* outf = reinterpret_cast<float*>(out);
  __hip_bfloat16* outb = reinterpret_cast<__hip_bfloat16*>(out);

  constexpr int NPF = 16;
  float buf[NPF];
#pragma unroll
  for (int j = 0; j < NPF; ++j) buf[j] = base[(size_t)j * N_SZ];

  for (int t0 = 0; t0 < T_SZ; t0 += NPF) {
#pragma unroll
    for (int j = 0; j < NPF; ++j) {
      const int t = t0 + j;
      const float cur = buf[j];
      if (t + NPF < T_SZ) buf[j] = base[(size_t)(t + NPF) * N_SZ];
      // w = (be*w + av*u) + bv*s   (numpy left-to-right, each op rounded)
      w = __fadd_rn(__fadd_rn(__fmul_rn(be, w), __fmul_rn(av, u)), __fmul_rn(bv, s));
      // u = al*(u - s) + om*(cur - w)
      u = __fadd_rn(__fmul_rn(al, __fsub_rn(u, s)), __fmul_rn(om, __fsub_rn(cur, w)));
      s = (u > 1.0f) ? 1.0f : 0.0f;
      const size_t o = obase + (size_t)t * N_SZ;
      if (isb) outb[o] = __float2bfloat16(s);  // 0/1 exact in bf16
      else outf[o] = s;
    }
  }
}

extern "C" void kernel_launch(void* const* d_in, const int* in_sizes, int n_in,
                              void* d_out, int out_size, void* d_ws, size_t ws_size,
                              hipStream_t stream) {
  const void* X = d_in[0];   // x [B,T,I]
  const void* Wm = d_in[1];  // W [H,I]
  float* ws = reinterpret_cast<float*>(d_ws);  // Wx fp32 [B,T,H]

  sgemm_bt<<<dim3((M_SZ / 128) * (N_SZ / 128)), dim3(256), 0, stream>>>(X, Wm, ws);

  lif_scan<<<dim3(B_SZ * 2), dim3(256), 0, stream>>>(
      ws, X, d_in[2], d_in[3], d_in[4], d_in[5], d_in[6], d_in[7], d_in[8], d_out);
}

// Round 3
// 667.570 us; speedup vs baseline: 1.2629x; 1.2629x over previous
//
#include <hip/hip_runtime.h>
#include <hip/hip_bf16.h>

// adLIF: Wx = x @ W^T (fp32 FMA GEMM, strictly sequential-K accumulation to
// mirror BLAS bit-for-bit), then sequential LIF scan over T with rounding-exact
// fp32 ops. Input dtype (fp32 vs bf16) detected ON DEVICE from x's bit pattern;
// kernels branch uniformly into template-specialized bodies.
// B=128, T=512, I=512, H=512. ws holds Wx fp32 [B,T,H] = 134217728 bytes.

#define M_SZ 65536  // B*T
#define H_SZ 512
#define K_SZ 512
#define B_SZ 128
#define T_SZ 512

#define AST 260  // A-tile LDS row stride (dwords): %32==4 -> 2-way (free) banks
#define BST 132  // B-tile LDS row stride (dwords): %32==4

__device__ __forceinline__ bool detect_bf16(const unsigned int* __restrict__ w) {
  int c = 0;
#pragma unroll
  for (int i = 0; i < 64; ++i) {
    unsigned int e = (w[i] >> 7) & 0xffu;
    c += (e >= 115u && e <= 131u) ? 1 : 0;
  }
  return c > 32;  // bf16 exponents cluster in [115,131]; fp32 mantissa bits don't
}

template <bool ISB>
__device__ __forceinline__ float4 ld4t(const void* __restrict__ p, size_t off) {
  if constexpr (!ISB) {
    return *reinterpret_cast<const float4*>(reinterpret_cast<const float*>(p) + off);
  } else {
    uint2 v = *reinterpret_cast<const uint2*>(reinterpret_cast<const unsigned short*>(p) + off);
    float4 r;
    r.x = __uint_as_float((v.x & 0xffffu) << 16);
    r.y = __uint_as_float(v.x & 0xffff0000u);
    r.z = __uint_as_float((v.y & 0xffffu) << 16);
    r.w = __uint_as_float(v.y & 0xffff0000u);
    return r;
  }
}

template <bool ISB>
__device__ __forceinline__ float ld1t(const void* __restrict__ p, int i) {
  if constexpr (!ISB) return reinterpret_cast<const float*>(p)[i];
  return __uint_as_float((unsigned int)(reinterpret_cast<const unsigned short*>(p)[i]) << 16);
}

__device__ __forceinline__ void gl_lds16(const void* g, void* l) {
  __builtin_amdgcn_global_load_lds(
      (const __attribute__((address_space(1))) void*)g,
      (__attribute__((address_space(3))) void*)l, 16, 0, 0);
}

// ---------------- GEMM: C[m][n] = sum_k X[m][k]*W[n][k], fp32, k ascending ----
// Tile 256(M) x 128(N) per 256-thread block; micro-tile 16x8; KS=16.
template <bool ISB>
__device__ __forceinline__ void gemm_body(const void* __restrict__ X,
                                          const void* __restrict__ Wm,
                                          float* __restrict__ C,
                                          float* __restrict__ As,
                                          float* __restrict__ Bs) {
  const int tid = threadIdx.x;
  const int r0 = tid >> 2;       // 0..63: staged row
  const int q0 = (tid & 3) * 4;  // 0,4,8,12: k-group
  const int tx = tid & 15;       // n-group
  const int ty = tid >> 4;       // m-group
  const size_t M0 = (size_t)(blockIdx.x >> 2) * 256;
  const int N0 = (blockIdx.x & 3) * 128;

  float acc[16][8];
#pragma unroll
  for (int i = 0; i < 16; ++i)
#pragma unroll
    for (int j = 0; j < 8; ++j) acc[i][j] = 0.0f;

  float4 pa[4], pb[2];
#pragma unroll
  for (int p = 0; p < 4; ++p) pa[p] = ld4t<ISB>(X, (M0 + r0 + 64 * p) * K_SZ + q0);
#pragma unroll
  for (int q = 0; q < 2; ++q) pb[q] = ld4t<ISB>(Wm, (size_t)(N0 + r0 + 64 * q) * K_SZ + q0);

  for (int kk = 0; kk < K_SZ; kk += 16) {
    __syncthreads();  // prior compute done -> LDS free
#pragma unroll
    for (int p = 0; p < 4; ++p) {
      As[(q0 + 0) * AST + r0 + 64 * p] = pa[p].x;
      As[(q0 + 1) * AST + r0 + 64 * p] = pa[p].y;
      As[(q0 + 2) * AST + r0 + 64 * p] = pa[p].z;
      As[(q0 + 3) * AST + r0 + 64 * p] = pa[p].w;
    }
#pragma unroll
    for (int q = 0; q < 2; ++q) {
      Bs[(q0 + 0) * BST + r0 + 64 * q] = pb[q].x;
      Bs[(q0 + 1) * BST + r0 + 64 * q] = pb[q].y;
      Bs[(q0 + 2) * BST + r0 + 64 * q] = pb[q].z;
      Bs[(q0 + 3) * BST + r0 + 64 * q] = pb[q].w;
    }
    __syncthreads();  // tile ready
    if (kk + 16 < K_SZ) {  // register prefetch of next chunk, in flight over compute
#pragma unroll
      for (int p = 0; p < 4; ++p)
        pa[p] = ld4t<ISB>(X, (M0 + r0 + 64 * p) * K_SZ + kk + 16 + q0);
#pragma unroll
      for (int q = 0; q < 2; ++q)
        pb[q] = ld4t<ISB>(Wm, (size_t)(N0 + r0 + 64 * q) * K_SZ + kk + 16 + q0);
    }
#pragma unroll
    for (int k = 0; k < 16; ++k) {
      float av[16], bv[8];
#pragma unroll
      for (int p = 0; p < 4; ++p) {
        const float4 t4 = *reinterpret_cast<const float4*>(As + k * AST + ty * 4 + 64 * p);
        av[p * 4 + 0] = t4.x; av[p * 4 + 1] = t4.y; av[p * 4 + 2] = t4.z; av[p * 4 + 3] = t4.w;
      }
#pragma unroll
      for (int q = 0; q < 2; ++q) {
        const float4 t4 = *reinterpret_cast<const float4*>(Bs + k * BST + tx * 4 + 64 * q);
        bv[q * 4 + 0] = t4.x; bv[q * 4 + 1] = t4.y; bv[q * 4 + 2] = t4.z; bv[q * 4 + 3] = t4.w;
      }
#pragma unroll
      for (int i = 0; i < 16; ++i)
#pragma unroll
        for (int j = 0; j < 8; ++j) acc[i][j] += av[i] * bv[j];  // contracts to FMA
    }
  }

#pragma unroll
  for (int p = 0; p < 4; ++p)
#pragma unroll
    for (int r = 0; r < 4; ++r) {
      const size_t m = M0 + 64 * p + ty * 4 + r;
      float* Cp = C + m * H_SZ + N0 + tx * 4;
      float4 v0 = {acc[p * 4 + r][0], acc[p * 4 + r][1], acc[p * 4 + r][2], acc[p * 4 + r][3]};
      float4 v1 = {acc[p * 4 + r][4], acc[p * 4 + r][5], acc[p * 4 + r][6], acc[p * 4 + r][7]};
      *reinterpret_cast<float4*>(Cp) = v0;
      *reinterpret_cast<float4*>(Cp + 64) = v1;
    }
}

__global__ __launch_bounds__(256) void sgemm_bt(const void* __restrict__ X,
                                                const void* __restrict__ Wm,
                                                float* __restrict__ C) {
  __shared__ float As[16 * AST];  // 16.6 KB
  __shared__ float Bs[16 * BST];  // 8.4 KB
  if (detect_bf16(reinterpret_cast<const unsigned int*>(X)))
    gemm_body<true>(X, Wm, C, As, Bs);
  else
    gemm_body<false>(X, Wm, C, As, Bs);
}

// ---------------- LIF scan: chunked LDS staging, double-buffered -------------
#define CH 32  // timesteps per chunk

template <bool ISB>
__device__ __forceinline__ void scan_body(
    const float* __restrict__ wx, const void* __restrict__ alpha_p,
    const void* __restrict__ beta_p, const void* __restrict__ a_p,
    const void* __restrict__ b_p, const void* __restrict__ u0p,
    const void* __restrict__ w0p, const void* __restrict__ s0p,
    void* __restrict__ out, float* __restrict__ buf) {
  const int tid = threadIdx.x;
  const int wave = tid >> 6;
  const int lane = tid & 63;
  const int bb = blockIdx.x >> 1;
  const int half = blockIdx.x & 1;
  const int h = half * 256 + tid;

  const float al = fminf(fmaxf(ld1t<ISB>(alpha_p, h), (float)0.8187307530779818),
                         (float)0.9607894391523232);
  const float be = fminf(fmaxf(ld1t<ISB>(beta_p, h), (float)0.9672161004820059),
                         (float)0.9917013044213351);
  const float av = fminf(fmaxf(ld1t<ISB>(a_p, h), -1.0f), 1.0f);
  const float bv = fminf(fmaxf(ld1t<ISB>(b_p, h), 0.0f), 2.0f);
  const float om = __fsub_rn(1.0f, al);

  const int bh = bb * H_SZ + h;
  float u = ld1t<ISB>(u0p, bh);
  float w = ld1t<ISB>(w0p, bh);
  float s = ld1t<ISB>(s0p, bh);

  const float* xbase = wx + (size_t)bb * T_SZ * H_SZ + half * 256;  // + t*H_SZ
  float* outf = reinterpret_cast<float*>(out);
  __hip_bfloat16* outb = reinterpret_cast<__hip_bfloat16*>(out);
  const size_t ob0 = (size_t)bb * T_SZ * H_SZ + h;

  // wave w stages timesteps w*8..w*8+7 of each chunk: 1 KB contiguous per instr
  auto issue = [&](int c) {
    float* dst = buf + (c & 1) * (CH * 256);
    const float* src = xbase + (size_t)c * CH * H_SZ;
#pragma unroll
    for (int i = 0; i < 8; ++i) {
      const int t = wave * 8 + i;
      gl_lds16(src + (size_t)t * H_SZ + lane * 4, dst + t * 256 + lane * 4);
    }
  };

  issue(0);
  for (int c = 0; c < T_SZ / CH; ++c) {
    __syncthreads();  // drains chunk-c loads (vmcnt 0) + guards buffer reuse
    if (c + 1 < T_SZ / CH) issue(c + 1);  // in flight over this chunk's compute
    const float* cb = buf + (c & 1) * (CH * 256);
#pragma unroll
    for (int j = 0; j < CH; ++j) {
      const float cur = cb[j * 256 + tid];
      // numpy left-to-right, each op individually rounded (no FMA contraction)
      w = __fadd_rn(__fadd_rn(__fmul_rn(be, w), __fmul_rn(av, u)), __fmul_rn(bv, s));
      u = __fadd_rn(__fmul_rn(al, __fsub_rn(u, s)), __fmul_rn(om, __fsub_rn(cur, w)));
      s = (u > 1.0f) ? 1.0f : 0.0f;
      const size_t o = ob0 + (size_t)(c * CH + j) * H_SZ;
      if constexpr (ISB) outb[o] = __float2bfloat16(s);  // 0/1 exact in bf16
      else outf[o] = s;
    }
  }
}

__global__ __launch_bounds__(256) void lif_scan(
    const float* __restrict__ wx, const void* __restrict__ X,
    const void* __restrict__ alpha_p, const void* __restrict__ beta_p,
    const void* __restrict__ a_p, const void* __restrict__ b_p,
    const void* __restrict__ u0p, const void* __restrict__ w0p,
    const void* __restrict__ s0p, void* __restrict__ out) {
  __shared__ float buf[2 * CH * 256];  // 64 KB double buffer
  if (detect_bf16(reinterpret_cast<const unsigned int*>(X)))
    scan_body<true>(wx, alpha_p, beta_p, a_p, b_p, u0p, w0p, s0p, out, buf);
  else
    scan_body<false>(wx, alpha_p, beta_p, a_p, b_p, u0p, w0p, s0p, out, buf);
}

extern "C" void kernel_launch(void* const* d_in, const int* in_sizes, int n_in,
                              void* d_out, int out_size, void* d_ws, size_t ws_size,
                              hipStream_t stream) {
  const void* X = d_in[0];   // x [B,T,I]
  const void* Wm = d_in[1];  // W [H,I]
  float* ws = reinterpret_cast<float*>(d_ws);  // Wx fp32 [B,T,H]

  sgemm_bt<<<dim3((M_SZ / 256) * (H_SZ / 128)), dim3(256), 0, stream>>>(X, Wm, ws);

  lif_scan<<<dim3(B_SZ * 2), dim3(256), 0, stream>>>(
      ws, X, d_in[2], d_in[3], d_in[4], d_in[5], d_in[6], d_in[7], d_in[8], d_out);
}